// Round 3
// baseline (132.176 us; speedup 1.0000x reference)
//
#include <hip/hip_runtime.h>
#include <hip/hip_bf16.h>

#define M_ROWS 8192
#define HALF_N 4096
#define D 128
#define INV_T 2.0f   // 1 / temperature(0.5)
#define NT 8         // B-tiles (128 cols each) per block chunk

typedef __attribute__((ext_vector_type(4))) float f32x4;
typedef __attribute__((ext_vector_type(8))) short bf16x8;
typedef unsigned int u32;
typedef __attribute__((ext_vector_type(4))) u32 u32x4;

__device__ __forceinline__ void gload_lds16(const void* g, void* l) {
    __builtin_amdgcn_global_load_lds(
        (const __attribute__((address_space(1))) u32*)g,
        (__attribute__((address_space(3))) u32*)l, 16, 0, 0);
}

// ---------------------------------------------------------------------------
// Kernel A: L2-normalize rows (fp32 in, bf16 out), zero rowsum accumulator.
// ---------------------------------------------------------------------------
__global__ __launch_bounds__(256) void k_normalize(
    const float* __restrict__ zi, const float* __restrict__ zj,
    __hip_bfloat16* __restrict__ zb, float* __restrict__ rowsum)
{
    int t = blockIdx.x * 256 + threadIdx.x;
    if (t < M_ROWS) rowsum[t] = 0.0f;   // re-init every launch (ws not re-poisoned)

    int row  = t >> 6;
    int lane = t & 63;
    const float* src = (row < HALF_N) ? (zi + (size_t)row * D)
                                      : (zj + (size_t)(row - HALF_N) * D);
    float2 v = *(const float2*)(src + lane * 2);
    float ss = v.x * v.x + v.y * v.y;
    #pragma unroll
    for (int o = 32; o >= 1; o >>= 1) ss += __shfl_xor(ss, o);
    float scale = 1.0f / fmaxf(sqrtf(ss), 1e-12f);

    __hip_bfloat162 o2;
    o2.x = __float2bfloat16(v.x * scale);
    o2.y = __float2bfloat16(v.y * scale);
    *(__hip_bfloat162*)(zb + (size_t)row * D + lane * 2) = o2;
}

// ---------------------------------------------------------------------------
// Kernel B: block = 128 rows x 1024 cols of sim. A-tile in registers (from
// L2), B-tiles double-buffered in LDS via global_load_lds (pre-swizzled
// global source -> linear LDS; XOR-swizzled ds_read). Counted vmcnt + raw
// s_barrier pipeline (T3/T4-lite). exp sums accumulate in registers across
// all 8 tiles; one shfl-reduce + 128 atomics per block at the end.
// ---------------------------------------------------------------------------
__global__ __launch_bounds__(256, 2) void k_simsum(
    const __hip_bfloat16* __restrict__ zb, float* __restrict__ rowsum)
{
    __shared__ char sB[2][32768];       // two 128x128 bf16 B-tiles

    const int ibase  = blockIdx.y * 128;     // row tile
    const int chunk  = blockIdx.x;           // col chunk (0..7)
    const int jbase0 = chunk * (NT * 128);
    const int tid    = threadIdx.x;
    const int wv     = tid >> 6, lane = tid & 63;
    const int lr     = lane & 15, lg = lane >> 4;
    const int rbase  = wv * 32;

    // A fragments: 32 rows x K=128 per wave, kept in 32 VGPRs.
    bf16x8 a[2][4];
    #pragma unroll
    for (int m = 0; m < 2; ++m)
        #pragma unroll
        for (int ks = 0; ks < 4; ++ks) {
            int row = ibase + rbase + m * 16 + lr;
            a[m][ks] = *(const bf16x8*)(zb + (size_t)row * D + (ks * 4 + lg) * 8);
        }

    // Stage one 128x128 B-tile into buf. Linear LDS dest (wave-uniform base
    // + lane*16); swizzle applied on the GLOBAL source address so that
    // lds[row][s] = global[row][s ^ (row&7)] (16B slots).
    auto stage = [&](int t, char* buf) {
        int jb = jbase0 + t * 128;
        #pragma unroll
        for (int i = 0; i < 8; ++i) {
            int c   = wv * 8 + i;            // 1KB chunk = 4 rows
            int row = c * 4 + lg;
            int gs  = lr ^ (row & 7);
            gload_lds16(zb + (size_t)(jb + row) * D + gs * 8, buf + c * 1024);
        }
    };

    float eacc[2][4] = {{0.f, 0.f, 0.f, 0.f}, {0.f, 0.f, 0.f, 0.f}};

    stage(0, sB[0]);

    #pragma unroll
    for (int t = 0; t < NT; ++t) {
        char* cur = sB[t & 1];
        if (t + 1 < NT) stage(t + 1, sB[(t + 1) & 1]);
        asm volatile("" ::: "memory");
        if (t + 1 < NT) {
            asm volatile("s_waitcnt vmcnt(8)" ::: "memory");  // cur's 8 landed; next 8 in flight
        } else {
            asm volatile("s_waitcnt vmcnt(0)" ::: "memory");
        }
        __builtin_amdgcn_s_barrier();
        asm volatile("" ::: "memory");

        f32x4 acc[2][8];
        #pragma unroll
        for (int m = 0; m < 2; ++m)
            #pragma unroll
            for (int n = 0; n < 8; ++n) acc[m][n] = (f32x4){0.f, 0.f, 0.f, 0.f};

        #pragma unroll
        for (int ks = 0; ks < 4; ++ks) {
            #pragma unroll
            for (int n = 0; n < 8; ++n) {
                int rowB = n * 16 + lr;
                bf16x8 b = *(const bf16x8*)(cur + rowB * 256 +
                            ((((ks << 2) + lg) ^ (lr & 7)) << 4));
                acc[0][n] = __builtin_amdgcn_mfma_f32_16x16x32_bf16(a[0][ks], b, acc[0][n], 0, 0, 0);
                acc[1][n] = __builtin_amdgcn_mfma_f32_16x16x32_bf16(a[1][ks], b, acc[1][n], 0, 0, 0);
            }
        }

        #pragma unroll
        for (int m = 0; m < 2; ++m)
            #pragma unroll
            for (int n = 0; n < 8; ++n)
                #pragma unroll
                for (int r = 0; r < 4; ++r)
                    eacc[m][r] += __expf(INV_T * acc[m][n][r]);

        asm volatile("" ::: "memory");
        __builtin_amdgcn_s_barrier();   // all reads of cur done before t+2 overwrites it
    }

    // Epilogue: reduce over the 16 col-lanes, one atomic per row (8 contenders).
    #pragma unroll
    for (int m = 0; m < 2; ++m)
        #pragma unroll
        for (int r = 0; r < 4; ++r) {
            float e = eacc[m][r];
            e += __shfl_xor(e, 1);
            e += __shfl_xor(e, 2);
            e += __shfl_xor(e, 4);
            e += __shfl_xor(e, 8);
            if (lr == 0)
                atomicAdd(&rowsum[ibase + rbase + m * 16 + lg * 4 + r], e);
        }
}

// ---------------------------------------------------------------------------
// Kernel C: per row, recompute self-dot and positive-pair dot (fp32 from
// bf16), lse = log(rowsum - exp(2*self) + exp(2*pos)), write lse - pos.
// ---------------------------------------------------------------------------
__global__ __launch_bounds__(256) void k_rowloss(
    const __hip_bfloat16* __restrict__ zb, const float* __restrict__ rowsum,
    float* __restrict__ rowloss)
{
    int t = blockIdx.x * 256 + threadIdx.x;
    int row = t >> 6, lane = t & 63;
    int pair = row ^ HALF_N;

    __hip_bfloat162 av = *(const __hip_bfloat162*)(zb + (size_t)row  * D + lane * 2);
    __hip_bfloat162 bv = *(const __hip_bfloat162*)(zb + (size_t)pair * D + lane * 2);
    float ax = __bfloat162float(av.x), ay = __bfloat162float(av.y);
    float bx = __bfloat162float(bv.x), by = __bfloat162float(bv.y);
    float sd = ax * ax + ay * ay;
    float pd = ax * bx + ay * by;
    #pragma unroll
    for (int o = 32; o >= 1; o >>= 1) {
        sd += __shfl_xor(sd, o);
        pd += __shfl_xor(pd, o);
    }
    if (lane == 0) {
        float rs  = rowsum[row];
        float val = rs - __expf(INV_T * sd) + __expf(INV_T * pd);
        rowloss[row] = logf(val) - INV_T * pd;
    }
}

// ---------------------------------------------------------------------------
// Kernel D: single-block tree reduction of rowloss[8192] -> mean.
// ---------------------------------------------------------------------------
__global__ __launch_bounds__(1024) void k_reduce(
    const float* __restrict__ rowloss, float* __restrict__ out)
{
    __shared__ float sm[16];
    int tid = threadIdx.x;
    float s = 0.f;
    #pragma unroll
    for (int i = 0; i < M_ROWS / 1024; ++i) s += rowloss[i * 1024 + tid];
    #pragma unroll
    for (int o = 32; o >= 1; o >>= 1) s += __shfl_xor(s, o);
    if ((tid & 63) == 0) sm[tid >> 6] = s;
    __syncthreads();
    if (tid == 0) {
        float tot = 0.f;
        #pragma unroll
        for (int w = 0; w < 16; ++w) tot += sm[w];
        out[0] = tot * (1.0f / (float)M_ROWS);
    }
}

// ---------------------------------------------------------------------------
extern "C" void kernel_launch(void* const* d_in, const int* in_sizes, int n_in,
                              void* d_out, int out_size, void* d_ws, size_t ws_size,
                              hipStream_t stream)
{
    const float* zi = (const float*)d_in[0];
    const float* zj = (const float*)d_in[1];

    float* rowsum  = (float*)d_ws;                               // 8192 f32
    float* rowloss = rowsum + M_ROWS;                            // 8192 f32
    __hip_bfloat16* zb = (__hip_bfloat16*)((char*)d_ws + 65536); // 8192x128 bf16

    k_normalize<<<dim3(M_ROWS * 64 / 256), 256, 0, stream>>>(zi, zj, zb, rowsum);
    k_simsum<<<dim3(8, 64), dim3(256), 0, stream>>>(zb, rowsum);
    k_rowloss<<<dim3(M_ROWS * 64 / 256), 256, 0, stream>>>(zb, rowsum, rowloss);
    k_reduce<<<dim3(1), dim3(1024), 0, stream>>>(rowloss, (float*)d_out);
}

// Round 4
// 38.768 us; speedup vs baseline: 3.4094x; 3.4094x over previous
//
#include <hip/hip_runtime.h>
#include <hip/hip_bf16.h>

#define M_ROWS 8192
#define HALF_N 4096
#define D 128
#define INV_T 2.0f   // 1 / temperature(0.5)
#define NT 4         // B-tiles (128 cols each) per block

typedef __attribute__((ext_vector_type(4))) float f32x4;
typedef __attribute__((ext_vector_type(8))) short bf16x8;
typedef unsigned int u32;
typedef __attribute__((ext_vector_type(4))) u32 u32x4;

// ---------------------------------------------------------------------------
// Kernel A: L2-normalize rows (fp32 in, bf16 out), zero rowsum accumulator.
// ---------------------------------------------------------------------------
__global__ __launch_bounds__(256) void k_normalize(
    const float* __restrict__ zi, const float* __restrict__ zj,
    __hip_bfloat16* __restrict__ zb, float* __restrict__ rowsum)
{
    int t = blockIdx.x * 256 + threadIdx.x;
    if (t < M_ROWS) rowsum[t] = 0.0f;   // re-init every launch (ws not re-poisoned)

    int row  = t >> 6;
    int lane = t & 63;
    const float* src = (row < HALF_N) ? (zi + (size_t)row * D)
                                      : (zj + (size_t)(row - HALF_N) * D);
    float2 v = *(const float2*)(src + lane * 2);
    float ss = v.x * v.x + v.y * v.y;
    #pragma unroll
    for (int o = 32; o >= 1; o >>= 1) ss += __shfl_xor(ss, o);
    float scale = 1.0f / fmaxf(sqrtf(ss), 1e-12f);

    __hip_bfloat162 o2;
    o2.x = __float2bfloat16(v.x * scale);
    o2.y = __float2bfloat16(v.y * scale);
    *(__hip_bfloat162*)(zb + (size_t)row * D + lane * 2) = o2;
}

// ---------------------------------------------------------------------------
// Kernel B: block = 128 rows x 512 cols of sim. A-tile in registers (L2),
// B-tiles double-buffered in LDS, staged via registers (T14): coalesced
// u32x4 global loads for tile t+1 issued BEFORE computing tile t, ds_write
// to XOR-swizzled LDS slots after the post-compute barrier. exp sums
// accumulate in registers across all 4 tiles; one shfl-reduce + 128 atomics
// per block (16-way contention, spread over 8192 addresses).
// ---------------------------------------------------------------------------
__global__ __launch_bounds__(256, 2) void k_simsum(
    const __hip_bfloat16* __restrict__ zb, float* __restrict__ rowsum)
{
    __shared__ char sB[2][32768];       // two 128x128 bf16 B-tiles

    const int ibase  = blockIdx.y * 128;      // row tile
    const int chunk  = blockIdx.x;            // col chunk (0..15)
    const int jbase0 = chunk * (NT * 128);
    const int tid    = threadIdx.x;
    const int wv     = tid >> 6, lane = tid & 63;
    const int lr     = lane & 15, lg = lane >> 4;
    const int rbase  = wv * 32;

    // A fragments: 32 rows x K=128 per wave, kept in 32 VGPRs (loaded from L2).
    bf16x8 a[2][4];
    #pragma unroll
    for (int m = 0; m < 2; ++m)
        #pragma unroll
        for (int ks = 0; ks < 4; ++ks) {
            int row = ibase + rbase + m * 16 + lr;
            a[m][ks] = *(const bf16x8*)(zb + (size_t)row * D + (ks * 4 + lg) * 8);
        }

    // Reg-staging: each thread carries 8 x 16B of the next B-tile.
    // Part i covers LDS rows (wv*8+i)*4 + lg, 16B slot lr (linear global read).
    u32x4 breg[8];
    auto load_tile = [&](int t) {
        int jb = jbase0 + t * 128;
        #pragma unroll
        for (int i = 0; i < 8; ++i) {
            int row = (wv * 8 + i) * 4 + lg;
            breg[i] = *(const u32x4*)(zb + (size_t)(jb + row) * D + lr * 8);
        }
    };
    auto write_tile = [&](char* buf) {
        #pragma unroll
        for (int i = 0; i < 8; ++i) {
            int row = (wv * 8 + i) * 4 + lg;
            *(u32x4*)(buf + row * 256 + ((lr ^ (row & 7)) << 4)) = breg[i];
        }
    };

    float eacc[2][4] = {{0.f, 0.f, 0.f, 0.f}, {0.f, 0.f, 0.f, 0.f}};

    load_tile(0);
    write_tile(sB[0]);
    __syncthreads();

    for (int t = 0; t < NT; ++t) {
        if (t + 1 < NT) load_tile(t + 1);   // prefetch to regs, hidden under compute
        const char* cur = sB[t & 1];

        f32x4 acc[2][8];
        #pragma unroll
        for (int m = 0; m < 2; ++m)
            #pragma unroll
            for (int n = 0; n < 8; ++n) acc[m][n] = (f32x4){0.f, 0.f, 0.f, 0.f};

        #pragma unroll
        for (int ks = 0; ks < 4; ++ks) {
            #pragma unroll
            for (int n = 0; n < 8; ++n) {
                int rowB = n * 16 + lr;
                bf16x8 b = *(const bf16x8*)(cur + rowB * 256 +
                            ((((ks << 2) + lg) ^ (lr & 7)) << 4));
                acc[0][n] = __builtin_amdgcn_mfma_f32_16x16x32_bf16(a[0][ks], b, acc[0][n], 0, 0, 0);
                acc[1][n] = __builtin_amdgcn_mfma_f32_16x16x32_bf16(a[1][ks], b, acc[1][n], 0, 0, 0);
            }
        }

        #pragma unroll
        for (int m = 0; m < 2; ++m)
            #pragma unroll
            for (int n = 0; n < 8; ++n)
                #pragma unroll
                for (int r = 0; r < 4; ++r)
                    eacc[m][r] += __expf(INV_T * acc[m][n][r]);

        __syncthreads();                     // everyone done reading cur
        if (t + 1 < NT) {
            write_tile(sB[(t + 1) & 1]);     // fill the other buffer
            __syncthreads();                 // writes visible before next compute
        }
    }

    // Epilogue: reduce over the 16 col-lanes, one atomic per row.
    #pragma unroll
    for (int m = 0; m < 2; ++m)
        #pragma unroll
        for (int r = 0; r < 4; ++r) {
            float e = eacc[m][r];
            e += __shfl_xor(e, 1);
            e += __shfl_xor(e, 2);
            e += __shfl_xor(e, 4);
            e += __shfl_xor(e, 8);
            if (lr == 0)
                atomicAdd(&rowsum[ibase + rbase + m * 16 + lg * 4 + r], e);
        }
}

// ---------------------------------------------------------------------------
// Kernel C: per row, recompute self-dot and positive-pair dot (fp32 from
// bf16), lse = log(rowsum - exp(2*self) + exp(2*pos)), write lse - pos.
// ---------------------------------------------------------------------------
__global__ __launch_bounds__(256) void k_rowloss(
    const __hip_bfloat16* __restrict__ zb, const float* __restrict__ rowsum,
    float* __restrict__ rowloss)
{
    int t = blockIdx.x * 256 + threadIdx.x;
    int row = t >> 6, lane = t & 63;
    int pair = row ^ HALF_N;

    __hip_bfloat162 av = *(const __hip_bfloat162*)(zb + (size_t)row  * D + lane * 2);
    __hip_bfloat162 bv = *(const __hip_bfloat162*)(zb + (size_t)pair * D + lane * 2);
    float ax = __bfloat162float(av.x), ay = __bfloat162float(av.y);
    float bx = __bfloat162float(bv.x), by = __bfloat162float(bv.y);
    float sd = ax * ax + ay * ay;
    float pd = ax * bx + ay * by;
    #pragma unroll
    for (int o = 32; o >= 1; o >>= 1) {
        sd += __shfl_xor(sd, o);
        pd += __shfl_xor(pd, o);
    }
    if (lane == 0) {
        float rs  = rowsum[row];
        float val = rs - __expf(INV_T * sd) + __expf(INV_T * pd);
        rowloss[row] = logf(val) - INV_T * pd;
    }
}

// ---------------------------------------------------------------------------
// Kernel D: single-block tree reduction of rowloss[8192] -> mean.
// ---------------------------------------------------------------------------
__global__ __launch_bounds__(1024) void k_reduce(
    const float* __restrict__ rowloss, float* __restrict__ out)
{
    __shared__ float sm[16];
    int tid = threadIdx.x;
    float s = 0.f;
    #pragma unroll
    for (int i = 0; i < M_ROWS / 1024; ++i) s += rowloss[i * 1024 + tid];
    #pragma unroll
    for (int o = 32; o >= 1; o >>= 1) s += __shfl_xor(s, o);
    if ((tid & 63) == 0) sm[tid >> 6] = s;
    __syncthreads();
    if (tid == 0) {
        float tot = 0.f;
        #pragma unroll
        for (int w = 0; w < 16; ++w) tot += sm[w];
        out[0] = tot * (1.0f / (float)M_ROWS);
    }
}

// ---------------------------------------------------------------------------
extern "C" void kernel_launch(void* const* d_in, const int* in_sizes, int n_in,
                              void* d_out, int out_size, void* d_ws, size_t ws_size,
                              hipStream_t stream)
{
    const float* zi = (const float*)d_in[0];
    const float* zj = (const float*)d_in[1];

    float* rowsum  = (float*)d_ws;                               // 8192 f32
    float* rowloss = rowsum + M_ROWS;                            // 8192 f32
    __hip_bfloat16* zb = (__hip_bfloat16*)((char*)d_ws + 65536); // 8192x128 bf16

    k_normalize<<<dim3(M_ROWS * 64 / 256), 256, 0, stream>>>(zi, zj, zb, rowsum);
    k_simsum<<<dim3(16, 64), dim3(256), 0, stream>>>(zb, rowsum);
    k_rowloss<<<dim3(M_ROWS * 64 / 256), 256, 0, stream>>>(zb, rowsum, rowloss);
    k_reduce<<<dim3(1), dim3(1024), 0, stream>>>(rowloss, (float*)d_out);
}